// Round 9
// baseline (362.645 us; speedup 1.0000x reference)
//
#include <hip/hip_runtime.h>

#define HWPX 4096   // 64*64 pixels

typedef short s8v  __attribute__((ext_vector_type(8)));   // 8 x bf16 (4 VGPR)
typedef float f4v  __attribute__((ext_vector_type(4)));   // 4 x f32  (MFMA C/D)

__device__ inline unsigned short f2bf(float f) {          // RNE f32 -> bf16
    unsigned u = __float_as_uint(f);
    return (unsigned short)((u + 0x7fffu + ((u >> 16) & 1u)) >> 16);
}
__device__ inline float bf2f(unsigned s) {
    return __uint_as_float(s << 16);
}

// ---------------------------------------------------------------------------
// Transpose+concat+cast: x_in/x_ref [768][4096] f32 -> xcat [4096 px][1536 ch] bf16
// ---------------------------------------------------------------------------
__global__ __launch_bounds__(256)
void tr_cat_k(const float* __restrict__ xa, const float* __restrict__ xb,
              short* __restrict__ xt)
{
    __shared__ __align__(16) short T[64 * 72];
    const int c0 = blockIdx.x * 64, p0 = blockIdx.y * 64, tid = threadIdx.x;
    for (int i = tid; i < 4096; i += 256) {
        int cl = i >> 6, pl = i & 63;
        int c = c0 + cl;
        float v = (c < 768) ? xa[(size_t)c * HWPX + p0 + pl]
                            : xb[(size_t)(c - 768) * HWPX + p0 + pl];
        T[pl * 72 + cl] = (short)f2bf(v);
    }
    __syncthreads();
    for (int i = tid; i < 512; i += 256) {
        int pl = i >> 3, part = i & 7;
        uint4 v = *(const uint4*)&T[pl * 72 + part * 8];
        *(uint4*)&xt[(size_t)(p0 + pl) * 1536 + c0 + part * 8] = v;
    }
}

// ---------------------------------------------------------------------------
// Fused weight fragment-pack for all 5 weights.
// dst[g][s][f][lane][8] bf16; s = cb*9+t; lane: lm=cout, quad=k-part.
// ---------------------------------------------------------------------------
__device__ inline void wpack1(const float* __restrict__ src, short* __restrict__ dst,
                              int i, int Cin, int Cout, int S, int NB)
{
    int e = i & 7, lane = (i >> 3) & 63;
    int lm = lane & 15, quad = lane >> 4;
    int rest = i >> 9;
    int f = rest % NB;
    int s = (rest / NB) % S;
    int g = rest / (NB * S);
    int cout = g * (NB * 16) + f * 16 + lm;
    int cb = s / 9, t = s % 9;
    int ch = cb * 32 + quad * 8 + e;
    dst[i] = (cout < Cout) ? (short)f2bf(src[((size_t)cout * Cin + ch) * 9 + t]) : 0;
}

#define C1 2654208   // w1: 3g*432s*4f*512
#define C2 2985984   // + w2: 3*54*4*512
#define C3 5640192   // + w3: 24*54*4*512
#define C4 6082560   // + w4: 1*432*2*512
#define C5 11390976  // + dw: 12*216*4*512

__global__ __launch_bounds__(256)
void wpack_all_k(const float* __restrict__ s1, const float* __restrict__ s2,
                 const float* __restrict__ s3, const float* __restrict__ s4,
                 const float* __restrict__ s5,
                 short* __restrict__ d1, short* __restrict__ d2,
                 short* __restrict__ d3, short* __restrict__ d4,
                 short* __restrict__ d5)
{
    int i = blockIdx.x * 256 + threadIdx.x;
    if (i < C1)      wpack1(s1, d1, i,      1536, 192,  432, 4);
    else if (i < C2) wpack1(s2, d2, i - C1, 192,  192,  54,  4);
    else if (i < C3) wpack1(s3, d3, i - C2, 192,  1536, 54,  4);
    else if (i < C4) wpack1(s4, d4, i - C3, 1536, 18,   432, 2);
    else if (i < C5) wpack1(s5, d5, i - C4, 768,  768,  216, 4);
}

// ---------------------------------------------------------------------------
// Flipped implicit-GEMM 3x3 conv, MFMA bf16. Block 256 thr = 4 waves.
// M = pixels (4 rows x 64), N = NB*16 couts (fragment-packed weights from
// global, prefetched one tap ahead). LDS: halo 6x66x40 = 31.7 KB.
// ---------------------------------------------------------------------------
template<int NB>
__global__ __launch_bounds__(256, 3)
void convf_k(const short* __restrict__ Xt, int CinStr,
             const short* __restrict__ Wp, int S, int chunks,
             short* __restrict__ Out, int Cstr, int splitStride)
{
    __shared__ __align__(16) short sH[6 * 66 * 40];   // 31.7 KB
    const int tid = threadIdx.x, lane = tid & 63, wv = tid >> 6;
    const int lm = lane & 15, quad = lane >> 4;
    const int r0 = blockIdx.x * 4;            // 4 pixel rows
    const int g  = blockIdx.y;                // cout group of NB*16
    const int cb0 = blockIdx.z * chunks;
    short* out = Out + (size_t)blockIdx.z * splitStride;

    f4v acc[4][NB];
#pragma unroll
    for (int ma = 0; ma < 4; ++ma)
#pragma unroll
        for (int nb = 0; nb < NB; ++nb)
#pragma unroll
            for (int r = 0; r < 4; ++r) acc[ma][nb][r] = 0.f;

    for (int cc = 0; cc < chunks; ++cc) {
        const int cb = cb0 + cc;
        const short* wpB = Wp + ((size_t)(g * S + cb * 9) * NB) * 512 + lane * 8;
        // prefetch tap-0 weight frags (overlaps halo staging + barrier)
        s8v bb[NB];
#pragma unroll
        for (int f = 0; f < NB; ++f)
            bb[f] = *(const s8v*)&wpB[(size_t)f * 512];

        // ---- stage halo: 6 rows x 66 px x 32 ch (zero-padded) ----
        for (int i = tid; i < 1584; i += 256) {
            int slot = i >> 2, part = i & 3;
            int hr = slot / 66, px = slot % 66;
            int gy = r0 - 1 + hr, gx = px - 1;
            uint4 v = {0, 0, 0, 0};
            if (gy >= 0 && gy < 64 && gx >= 0 && gx < 64)
                v = *(const uint4*)&Xt[(size_t)(gy * 64 + gx) * CinStr + cb * 32 + part * 8];
            *(uint4*)&sH[slot * 40 + part * 8] = v;
        }
        __syncthreads();

#pragma unroll
        for (int t = 0; t < 9; ++t) {
            const int ty = t / 3, tx = t % 3;
            // prefetch next tap (t=8 overreads into the next carved region)
            s8v nxt[NB];
#pragma unroll
            for (int f = 0; f < NB; ++f)
                nxt[f] = *(const s8v*)&wpB[(size_t)((t + 1) * NB + f) * 512];
            s8v a[4];
#pragma unroll
            for (int ma = 0; ma < 4; ++ma)
                a[ma] = *(const s8v*)&sH[((wv + ty) * 66 + ma * 16 + lm + tx) * 40 + quad * 8];
#pragma unroll
            for (int ma = 0; ma < 4; ++ma)
#pragma unroll
                for (int nb = 0; nb < NB; ++nb)
                    acc[ma][nb] = __builtin_amdgcn_mfma_f32_16x16x32_bf16(
                        a[ma], bb[nb], acc[ma][nb], 0, 0, 0);
#pragma unroll
            for (int f = 0; f < NB; ++f) bb[f] = nxt[f];
        }
        __syncthreads();
    }

    const int py = (r0 + wv) * 64;
#pragma unroll
    for (int ma = 0; ma < 4; ++ma)
#pragma unroll
        for (int nb = 0; nb < NB; ++nb)
#pragma unroll
            for (int r = 0; r < 4; ++r)
                out[(size_t)(py + ma * 16 + quad * 4 + r) * Cstr
                    + g * (NB * 16) + nb * 16 + lm] = (short)f2bf(acc[ma][nb][r]);
}

// ---------------------------------------------------------------------------
// Sum bf16 K-split partials, optional relu, -> bf16
// ---------------------------------------------------------------------------
__global__ __launch_bounds__(256)
void ep_sumb_k(const short* __restrict__ P, short* __restrict__ outb,
               int nsplit, size_t splitStride, int n8, int relu)
{
    int i = blockIdx.x * 256 + threadIdx.x;
    if (i >= n8) return;
    size_t base = (size_t)i * 8;
    float s[8];
#pragma unroll
    for (int j = 0; j < 8; ++j) s[j] = 0.f;
    for (int sp = 0; sp < nsplit; ++sp) {
        uint4 v = *(const uint4*)&P[sp * splitStride + base];
        s[0] += bf2f(v.x & 0xffffu); s[1] += bf2f(v.x >> 16);
        s[2] += bf2f(v.y & 0xffffu); s[3] += bf2f(v.y >> 16);
        s[4] += bf2f(v.z & 0xffffu); s[5] += bf2f(v.z >> 16);
        s[6] += bf2f(v.w & 0xffffu); s[7] += bf2f(v.w >> 16);
    }
    if (relu) {
#pragma unroll
        for (int j = 0; j < 8; ++j) s[j] = fmaxf(s[j], 0.f);
    }
    uint4 o;
    o.x = f2bf(s[0]) | ((unsigned)f2bf(s[1]) << 16);
    o.y = f2bf(s[2]) | ((unsigned)f2bf(s[3]) << 16);
    o.z = f2bf(s[4]) | ((unsigned)f2bf(s[5]) << 16);
    o.w = f2bf(s[6]) | ((unsigned)f2bf(s[7]) << 16);
    *(uint4*)&outb[base] = o;
}

// conv4 epilogue: partials bf16 [nsplit][4096][32] -> offs f32 [18][4096]
__global__ __launch_bounds__(256)
void ep_offs_k(const short* __restrict__ P, float* __restrict__ offs, int nsplit)
{
    int i = blockIdx.x * 256 + threadIdx.x;
    if (i >= 18 * HWPX) return;
    int m = i >> 12, px = i & 4095;
    float s = 0.f;
    for (int sp = 0; sp < nsplit; ++sp)
        s += bf2f((unsigned short)P[((size_t)sp * HWPX + px) * 32 + m]);
    offs[i] = s;
}

// ---------------------------------------------------------------------------
// Bilinear sampling -> Smp in MFMA fragment-packed order:
// Smp[pg][s][ma][lane][8]. Grid (256 px-blocks, 4 g-quarters).
// ---------------------------------------------------------------------------
__global__ __launch_bounds__(256)
void sample_k(const short* __restrict__ xcat, const float* __restrict__ offs,
              short* __restrict__ Smp)
{
    __shared__ int   s_mi[9][16][4];
    __shared__ float s_mw[9][16][4];
    const int tid = threadIdx.x;
    const int p0  = blockIdx.x * 16;
    const int gb  = blockIdx.y * 24;   // 24 of 96 channel-groups

    if (tid < 144) {
        int t = tid / 16, p = tid % 16;
        int pxg = p0 + p;
        int r = pxg >> 6, x = pxg & 63;
        float dy = offs[(size_t)(2 * t)     * HWPX + pxg];
        float dx = offs[(size_t)(2 * t + 1) * HWPX + pxg];
        float py  = (float)(r - 1 + t / 3) + dy;
        float pxf = (float)(x - 1 + t % 3) + dx;
        py  = fminf(fmaxf(py,  -1e6f), 1e6f);
        pxf = fminf(fmaxf(pxf, -1e6f), 1e6f);
        float y0f = floorf(py), x0f = floorf(pxf);
        float wy1 = py - y0f, wx1 = pxf - x0f;
        float wy0 = 1.f - wy1, wx0 = 1.f - wx1;
        bool vy0 = (y0f >=  0.f) && (y0f <= 63.f);
        bool vy1 = (y0f >= -1.f) && (y0f <= 62.f);
        bool vx0 = (x0f >=  0.f) && (x0f <= 63.f);
        bool vx1 = (x0f >= -1.f) && (x0f <= 62.f);
        int y0 = (int)fminf(fmaxf(y0f,       0.f), 63.f);
        int y1 = (int)fminf(fmaxf(y0f + 1.f, 0.f), 63.f);
        int x0 = (int)fminf(fmaxf(x0f,       0.f), 63.f);
        int x1 = (int)fminf(fmaxf(x0f + 1.f, 0.f), 63.f);
        s_mi[t][p][0] = y0 * 64 + x0;  s_mw[t][p][0] = (vy0 && vx0) ? wy0 * wx0 : 0.f;
        s_mi[t][p][1] = y0 * 64 + x1;  s_mw[t][p][1] = (vy0 && vx1) ? wy0 * wx1 : 0.f;
        s_mi[t][p][2] = y1 * 64 + x0;  s_mw[t][p][2] = (vy1 && vx0) ? wy1 * wx0 : 0.f;
        s_mi[t][p][3] = y1 * 64 + x1;  s_mw[t][p][3] = (vy1 && vx1) ? wy1 * wx1 : 0.f;
    }
    __syncthreads();

    for (int i = tid; i < 16 * 9 * 24; i += 256) {
        int p = i / 216, rest = i % 216;
        int t = rest / 24, g = gb + rest % 24;
        float a[8];
#pragma unroll
        for (int j = 0; j < 8; ++j) a[j] = 0.f;
#pragma unroll
        for (int c = 0; c < 4; ++c) {
            float w = s_mw[t][p][c];
            const short* src = xcat + (size_t)s_mi[t][p][c] * 1536 + 768 + g * 8;
            uint4 v = *(const uint4*)src;
            a[0] += w * bf2f(v.x & 0xffffu); a[1] += w * bf2f(v.x >> 16);
            a[2] += w * bf2f(v.y & 0xffffu); a[3] += w * bf2f(v.y >> 16);
            a[4] += w * bf2f(v.z & 0xffffu); a[5] += w * bf2f(v.z >> 16);
            a[6] += w * bf2f(v.w & 0xffffu); a[7] += w * bf2f(v.w >> 16);
        }
        uint4 o;
        o.x = f2bf(a[0]) | ((unsigned)f2bf(a[1]) << 16);
        o.y = f2bf(a[2]) | ((unsigned)f2bf(a[3]) << 16);
        o.z = f2bf(a[4]) | ((unsigned)f2bf(a[5]) << 16);
        o.w = f2bf(a[6]) | ((unsigned)f2bf(a[7]) << 16);
        int px = p0 + p;
        int pg = px >> 6, ma = (px >> 4) & 3, lmx = px & 15;
        int cb = g >> 2, qd = g & 3;
        size_t addr = ((((size_t)pg * 216 + cb * 9 + t) * 4 + ma) * 64 + qd * 16 + lmx) * 8;
        *(uint4*)&Smp[addr] = o;
    }
}

// ---------------------------------------------------------------------------
// Deform GEMM, zero-LDS, register-double-buffered (2-deep K pipeline).
// Grid (32 n, 6 m, 6 ksplit): n fastest => m-blocks sharing an Smp n-tile
// land on one XCD (strides 32 and 192, both ≡0 mod 8) => B L2-resident.
// ksplit 6 => 1152 blocks = 4.5 blocks/CU for latency hiding.
// ---------------------------------------------------------------------------
__global__ __launch_bounds__(256, 3)
void dgemm_k(const short* __restrict__ Ap, const short* __restrict__ Bp,
             short* __restrict__ P)
{
    const int tid = threadIdx.x, lane = tid & 63, wv = tid >> 6;
    const int lm = lane & 15, quad = lane >> 4;
    const int mg = blockIdx.y * 2 + (wv >> 1);    // 64-cout group 0..11
    const int pg = blockIdx.x * 2 + (wv & 1);     // 64-px group 0..63
    const int s0 = blockIdx.z * 36;
    const short* ap = Ap + (((size_t)mg * 216 + s0) * 4 * 64 + lane) * 8;
    const short* bp = Bp + (((size_t)pg * 216 + s0) * 4 * 64 + lane) * 8;

    f4v acc[4][4];
#pragma unroll
    for (int ma = 0; ma < 4; ++ma)
#pragma unroll
        for (int nb = 0; nb < 4; ++nb)
#pragma unroll
            for (int r = 0; r < 4; ++r) acc[ma][nb][r] = 0.f;

    s8v a0[4], b0[4], a1[4], b1[4];
#pragma unroll
    for (int f = 0; f < 4; ++f) {
        a0[f] = *(const s8v*)&ap[(size_t)f * 512];
        b0[f] = *(const s8v*)&bp[(size_t)f * 512];
    }

    for (int s = 0; s < 36; s += 2) {
#pragma unroll
        for (int f = 0; f < 4; ++f) {
            a1[f] = *(const s8v*)&ap[(size_t)((s + 1) * 4 + f) * 512];
            b1[f] = *(const s8v*)&bp[(size_t)((s + 1) * 4 + f) * 512];
        }
#pragma unroll
        for (int ma = 0; ma < 4; ++ma)
#pragma unroll
            for (int nb = 0; nb < 4; ++nb)
                acc[ma][nb] = __builtin_amdgcn_mfma_f32_16x16x32_bf16(
                    a0[ma], b0[nb], acc[ma][nb], 0, 0, 0);
#pragma unroll
        for (int f = 0; f < 4; ++f) {
            a0[f] = *(const s8v*)&ap[(size_t)((s + 2) * 4 + f) * 512];
            b0[f] = *(const s8v*)&bp[(size_t)((s + 2) * 4 + f) * 512];
        }
#pragma unroll
        for (int ma = 0; ma < 4; ++ma)
#pragma unroll
            for (int nb = 0; nb < 4; ++nb)
                acc[ma][nb] = __builtin_amdgcn_mfma_f32_16x16x32_bf16(
                    a1[ma], b1[nb], acc[ma][nb], 0, 0, 0);
    }

    short* p = P + (size_t)blockIdx.z * 768 * HWPX;
#pragma unroll
    for (int ma = 0; ma < 4; ++ma)
#pragma unroll
        for (int nb = 0; nb < 4; ++nb)
#pragma unroll
            for (int r = 0; r < 4; ++r)
                p[(size_t)(mg * 64 + ma * 16 + quad * 4 + r) * HWPX
                  + pg * 64 + nb * 16 + lm] = (short)f2bf(acc[ma][nb][r]);
}

// out f32 = sum of 6 bf16 partials
__global__ __launch_bounds__(256)
void ep_dg_k(const short* __restrict__ P, float* __restrict__ out)
{
    int i = blockIdx.x * 256 + threadIdx.x;
    if (i >= 768 * HWPX / 8) return;
    size_t base = (size_t)i * 8;
    float s[8];
#pragma unroll
    for (int j = 0; j < 8; ++j) s[j] = 0.f;
    for (int sp = 0; sp < 6; ++sp) {
        uint4 v = *(const uint4*)&P[(size_t)sp * 768 * HWPX + base];
        s[0] += bf2f(v.x & 0xffffu); s[1] += bf2f(v.x >> 16);
        s[2] += bf2f(v.y & 0xffffu); s[3] += bf2f(v.y >> 16);
        s[4] += bf2f(v.z & 0xffffu); s[5] += bf2f(v.z >> 16);
        s[6] += bf2f(v.w & 0xffffu); s[7] += bf2f(v.w >> 16);
    }
    float4 o0 = make_float4(s[0], s[1], s[2], s[3]);
    float4 o1 = make_float4(s[4], s[5], s[6], s[7]);
    *(float4*)&out[base]     = o0;
    *(float4*)&out[base + 4] = o1;
}

// ---------------------------------------------------------------------------
extern "C" void kernel_launch(void* const* d_in, const int* in_sizes, int n_in,
                              void* d_out, int out_size, void* d_ws, size_t ws_size,
                              hipStream_t stream)
{
    const float* x_in  = (const float*)d_in[0];
    const float* x_ref = (const float*)d_in[1];
    const float* w1    = (const float*)d_in[2];
    const float* w2    = (const float*)d_in[3];
    const float* w3    = (const float*)d_in[4];
    const float* ow    = (const float*)d_in[5];
    const float* dw    = (const float*)d_in[6];
    float* out = (float*)d_out;

    char* w = (char*)d_ws;
    size_t off = 0;
    auto carve = [&](size_t bytes) {
        void* p = w + off;
        off += (bytes + 255) & ~(size_t)255;
        return p;
    };
    // carve order chosen so xcat+R are contiguous (both dead after sample_k)
    short* w1p  = (short*)carve((size_t)C1 * 2);                 //  5.31 MB
    short* w2p  = (short*)carve((size_t)(C2 - C1) * 2);          //  0.66 MB
    short* w3p  = (short*)carve((size_t)(C3 - C2) * 2);          //  5.31 MB
    short* w4p  = (short*)carve((size_t)(C4 - C3) * 2);          //  0.88 MB
    short* dwp  = (short*)carve((size_t)(C5 - C4) * 2);          // 10.62 MB
    float* offs = (float*)carve((size_t)18 * 4096 * 4);          //  0.29 MB
    short* Smp  = (short*)carve((size_t)4096 * 6912 * 2);        // 56.62 MB
    short* xcat = (short*)carve((size_t)4096 * 1536 * 2);        // 12.58 MB
    char*  R    = (char*)carve((size_t)2 * 768 * 4096 * 4);      // 25.17 MB
    short* rh1  = (short*)R;                    // [4096][192] bf16
    short* rh2  = (short*)(R + 1572864);        // [4096][192] bf16
    short* est  = (short*)(R + 3145728);        // [4096][1536] bf16
    short* Pcv  = Smp;                          // conv partials (Smp idle til sample)
    short* Pdg  = xcat;                         // dgemm partials [6][768][4096] bf16
                                                //  = xcat+R (37.75 MB, exact fit)

    tr_cat_k<<<dim3(24, 64), 256, 0, stream>>>(x_in, x_ref, xcat);
    wpack_all_k<<<(C5 + 255) / 256, 256, 0, stream>>>(w1, w2, w3, ow, dw,
                                                      w1p, w2p, w3p, w4p, dwp);

    const int n8 = 4096 * 192 / 8;
    // conv1: 1536->192 relu; N=64, ksplit 16 x 3 chunks; partials in Smp
    convf_k<4><<<dim3(16, 3, 16), 256, 0, stream>>>(xcat, 1536, w1p, 432, 3,
                                                    Pcv, 192, 4096 * 192);
    ep_sumb_k<<<(n8 + 255) / 256, 256, 0, stream>>>(Pcv, rh1, 16, (size_t)4096 * 192, n8, 1);
    // conv2: 192->192 relu; N=64, ksplit 6 x 1 chunk
    convf_k<4><<<dim3(16, 3, 6), 256, 0, stream>>>(rh1, 192, w2p, 54, 1,
                                                   Pcv, 192, 4096 * 192);
    ep_sumb_k<<<(n8 + 255) / 256, 256, 0, stream>>>(Pcv, rh2, 6, (size_t)4096 * 192, n8, 1);
    // conv3: 192->1536; N=64, ksplit 2 x 3 chunks; partials in Smp -> est
    convf_k<4><<<dim3(16, 24, 2), 256, 0, stream>>>(rh2, 192, w3p, 54, 3,
                                                    Pcv, 1536, 4096 * 1536);
    {
        const int n8c3 = 4096 * 1536 / 8;
        ep_sumb_k<<<(n8c3 + 255) / 256, 256, 0, stream>>>(Pcv, est, 2, (size_t)4096 * 1536, n8c3, 0);
    }
    // conv4: 1536->18(pad 32); N=32, ksplit 48 x 1 chunk; partials in Smp
    convf_k<2><<<dim3(16, 1, 48), 256, 0, stream>>>(est, 1536, w4p, 432, 1,
                                                    Pcv, 32, 4096 * 32);
    ep_offs_k<<<(18 * HWPX + 255) / 256, 256, 0, stream>>>(Pcv, offs, 48);
    // deformable conv: fragment-packed sampling (4 g-quarters), zero-LDS GEMM
    sample_k<<<dim3(256, 4), 256, 0, stream>>>(xcat, offs, Smp);
    dgemm_k<<<dim3(32, 6, 6), 256, 0, stream>>>(dwp, Smp, Pdg);
    ep_dg_k<<<(768 * HWPX / 8 + 255) / 256, 256, 0, stream>>>(Pdg, out);
}